// Round 9
// baseline (247.632 us; speedup 1.0000x reference)
//
#include <hip/hip_runtime.h>
#include <cstdint>
#include <cstddef>

// Problem constants: B=2, S=2048, D=1024, H=16, dk=64. M = B*S = 4096.
#define S_LEN 2048
#define NH    16
#define DKH   64
#define DEMB  1024
#define MTOT  4096

typedef float f32x4 __attribute__((ext_vector_type(4)));
typedef __bf16 bf16x8 __attribute__((ext_vector_type(8)));
typedef _Float16 f16;
typedef f16 f16x2 __attribute__((ext_vector_type(2)));
typedef f16 f16x4 __attribute__((ext_vector_type(4)));
typedef f16 f16x8 __attribute__((ext_vector_type(8)));
typedef unsigned short u16;
typedef unsigned int u32;
typedef u16 u16x8 __attribute__((ext_vector_type(8)));
typedef u16 u16x4 __attribute__((ext_vector_type(4)));
typedef u32 u32x4 __attribute__((ext_vector_type(4)));

static __device__ __forceinline__ u16 f2bf(float f) {
  u32 u = __builtin_bit_cast(u32, f);
  u += 0x7fffu + ((u >> 16) & 1u);          // RNE
  return (u16)(u >> 16);
}
static __device__ __forceinline__ float bf2f(u16 b) {
  return __builtin_bit_cast(float, ((u32)b) << 16);
}
static __device__ __forceinline__ bf16x8 ldfrag(const u16* p) {
  return __builtin_bit_cast(bf16x8, *(const u16x8*)p);
}
static __device__ __forceinline__ f16x8 ldfragh8(const u16* p) {
  return __builtin_bit_cast(f16x8, *(const u16x8*)p);
}
static __device__ __forceinline__ f32x4 mfma16(bf16x8 a, bf16x8 b, f32x4 c) {
  return __builtin_amdgcn_mfma_f32_16x16x32_bf16(a, b, c, 0, 0, 0);
}
static __device__ __forceinline__ f32x4 mfmah32(f16x8 a, f16x8 b, f32x4 c) {
  return __builtin_amdgcn_mfma_f32_16x16x32_f16(a, b, c, 0, 0, 0);
}
static __device__ __forceinline__ void gl2lds16(const void* g, void* l) {
  __builtin_amdgcn_global_load_lds((__attribute__((address_space(1))) void*)g,
                                   (__attribute__((address_space(3))) void*)l,
                                   16, 0, 0);
}
// pack 2 fp32 -> u32 of 2 f16 (RTZ)
static __device__ __forceinline__ u32 pkh2(float a, float b) {
  return __builtin_bit_cast(u32, __builtin_amdgcn_cvt_pkrtz(a, b));
}
static __device__ __forceinline__ f16x4 pkh4(float a, float b, float c, float d) {
  f16x2 lo = __builtin_bit_cast(f16x2, __builtin_amdgcn_cvt_pkrtz(a, b));
  f16x2 hi = __builtin_bit_cast(f16x2, __builtin_amdgcn_cvt_pkrtz(c, d));
  return __builtin_shufflevector(lo, hi, 0, 1, 2, 3);
}

// 1/sqrt(dk) * log2(e): folded into the Q projection so attention scores are
// already in the exp2 domain.
#define SCL_Q (0.125f * 1.44269504088896340736f)

// ---------------- fp32 -> bf16 convert: QKV weights only ---------------------
// (activations are converted in-flight by qkv_gemm; WO rides on merge_ctx)
__global__ __launch_bounds__(256) void cvt_w(
    const float* __restrict__ wq, const float* __restrict__ wk,
    const float* __restrict__ wv, u16* __restrict__ dW) {
  const int b = blockIdx.x;                       // 0..3071
  const int seg = b >> 10;
  const float* s = (seg == 0) ? wq : (seg == 1) ? wk : wv;
  u16* d = dW + (size_t)seg * (DEMB * DEMB);
  const int i = ((b & 1023) * 256 + threadIdx.x) * 4;
  f32x4 f = *(const f32x4*)(s + i);
  u16x4 o;
  o[0] = f2bf(f[0]); o[1] = f2bf(f[1]); o[2] = f2bf(f[2]); o[3] = f2bf(f[3]);
  *(u16x4*)(d + i) = o;
}

// ---------------- fused QKV projection GEMM ----------------------------------
// Round-7 structure (128x128 tile, BK=32, 2-phase dbuf, XCD swizzle over 768)
// with ONE change: the A operand (activations) is staged DIRECTLY from the
// fp32 inputs — T14 issue-early/write-late split:
//   LOADA(next) issues f32x4 loads; comp(cur) runs (hides HBM latency);
//   STOREA converts (same f2bf RNE -> bit-identical) + ds_write_b128.
// This deletes cvt_all's 48MB read + 24MB write of pure copy work.
__global__ __launch_bounds__(256) void qkv_gemm(
    const float* __restrict__ qf, const float* __restrict__ kf,
    const float* __restrict__ vf, const u16* __restrict__ W,
    const float* __restrict__ bq, const float* __restrict__ bk,
    const float* __restrict__ bv,
    u16* __restrict__ qh, u16* __restrict__ kh, u16* __restrict__ vt) {
  __shared__ __align__(16) u16 sA0[128 * 32], sA1[128 * 32];  // 8 KB each
  __shared__ __align__(16) u16 sB0[128 * 32], sB1[128 * 32];  // 8 KB each
  const int t = threadIdx.x;
  const int l = t & 63, w = t >> 6;
  const int ll = l & 15, lg = l >> 4;
  // bijective XCD swizzle over 768 blocks (8 XCDs x 96)
  const int orig = blockIdx.x + 24 * blockIdx.y;
  const int xcd = orig & 7, q = orig >> 3;        // q 0..95
  const int nb = q >> 2;                          // 0..23
  const int mb = xcd * 4 + (q & 3);               // 0..31
  const int which = nb >> 3;           // 0=Q,1=K,2=V
  const float* A = (which == 0) ? qf : ((which == 1) ? kf : vf);
  const int wr = (w >> 1) * 64, wc = (w & 1) * 64;

  f32x4 acc[4][4] = {};

  // per-thread staging geometry (2 chunks per operand per K-step)
  const int c0 = t, c1 = 256 + t;
  const int row0 = c0 >> 2, row1 = c1 >> 2;
  const int gc0 = (c0 & 3) ^ ((row0 >> 1) & 3);
  const int gc1 = (c1 & 3) ^ ((row1 >> 1) & 3);
  const float* asrc0 = A + (size_t)(mb * 128 + row0) * DEMB + gc0 * 8;
  const float* asrc1 = A + (size_t)(mb * 128 + row1) * DEMB + gc1 * 8;
  const u16* bsrc0 = W + (size_t)(nb * 128 + row0) * DEMB + gc0 * 8;
  const u16* bsrc1 = W + (size_t)(nb * 128 + row1) * DEMB + gc1 * 8;

  f32x4 va[4];
  auto LOADA = [&](int kt) {
    const int k0 = kt * 32;
    va[0] = *(const f32x4*)(asrc0 + k0);
    va[1] = *(const f32x4*)(asrc0 + k0 + 4);
    va[2] = *(const f32x4*)(asrc1 + k0);
    va[3] = *(const f32x4*)(asrc1 + k0 + 4);
  };
  auto STOREA = [&](u16* dA) {
#pragma unroll
    for (int i = 0; i < 2; ++i) {
      u16x8 o;
#pragma unroll
      for (int r = 0; r < 4; ++r) o[r] = f2bf(va[2 * i][r]);
#pragma unroll
      for (int r = 0; r < 4; ++r) o[4 + r] = f2bf(va[2 * i + 1][r]);
      *(u16x8*)&dA[(i * 256 + t) * 8] = o;
    }
  };
  auto STGB = [&](int kt, u16* dB) {
    const int k0 = kt * 32;
    gl2lds16(bsrc0 + k0, dB + c0 * 8);
    gl2lds16(bsrc1 + k0, dB + c1 * 8);
  };

  auto comp = [&](const u16* cA, const u16* cB) {
    bf16x8 af[4], bfr[4];
#pragma unroll
    for (int i2 = 0; i2 < 4; ++i2) {
      const int row = wr + i2 * 16 + ll;
      af[i2] = ldfrag(&cA[row * 32 + (lg ^ ((row >> 1) & 3)) * 8]);
    }
#pragma unroll
    for (int j2 = 0; j2 < 4; ++j2) {
      const int row = wc + j2 * 16 + ll;
      bfr[j2] = ldfrag(&cB[row * 32 + (lg ^ ((row >> 1) & 3)) * 8]);
    }
#pragma unroll
    for (int i2 = 0; i2 < 4; ++i2)
#pragma unroll
      for (int j2 = 0; j2 < 4; ++j2)
        acc[i2][j2] = mfma16(af[i2], bfr[j2], acc[i2][j2]);
  };

  // ---- 2-phase double-buffered main loop over 32 K-steps ----
  LOADA(0); STGB(0, sB0); STOREA(sA0);
  __syncthreads();
  for (int kt2 = 0; kt2 < 16; ++kt2) {
    LOADA(2 * kt2 + 1);                 // issue next A loads (fp32)
    STGB(2 * kt2 + 1, sB1);             // issue next B gl2lds
    comp(sA0, sB0);                     // HBM latency hides under MFMA
    STOREA(sA1);                        // cvt + ds_write after compute
    __syncthreads();
    if (kt2 < 15) { LOADA(2 * kt2 + 2); STGB(2 * kt2 + 2, sB0); }
    comp(sA1, sB1);
    if (kt2 < 15) STOREA(sA0);
    __syncthreads();
  }

  const float* bias = (which == 0) ? bq : ((which == 1) ? bk : bv);
  const int b = (mb * 128) >> 11;                // tile never crosses batch

  if (which == 2) {
    // V: f16 register scatter to [bh][dk][s]; 4 consecutive s per 8B store
#pragma unroll
    for (int j2 = 0; j2 < 4; ++j2) {
      const int nl = (nb * 128 + wc + j2 * 16 + ll) & 1023;
      const int h = nl >> 6, dk = nl & 63;
      const float bb = bias[nl];
      u16* base = vt + ((size_t)((b * NH + h) * DKH + dk)) * S_LEN;
#pragma unroll
      for (int i2 = 0; i2 < 4; ++i2) {
        const int s = (mb * 128 + wr + i2 * 16 + lg * 4) & 2047;
        const f16x4 pk = pkh4(acc[i2][j2][0] + bb, acc[i2][j2][1] + bb,
                              acc[i2][j2][2] + bb, acc[i2][j2][3] + bb);
        *(u16x4*)&base[s] = __builtin_bit_cast(u16x4, pk);
      }
    }
  } else {
    u16* outp = (which == 0) ? qh : kh;
    const float scl = (which == 0) ? SCL_Q : 1.0f;
#pragma unroll
    for (int j2 = 0; j2 < 4; ++j2) {
      const int nl = (nb * 128 + wc + j2 * 16 + ll) & 1023;
      const int h = nl >> 6, dk = nl & 63;
      const float bb = bias[nl];
#pragma unroll
      for (int i2 = 0; i2 < 4; ++i2) {
#pragma unroll
        for (int r = 0; r < 4; ++r) {
          const int s = (mb * 128 + wr + i2 * 16 + lg * 4 + r) & 2047;
          const float val = (acc[i2][j2][r] + bb) * scl;
          outp[((size_t)((b * NH + h) * S_LEN + s)) * DKH + dk] = f2bf(val);
        }
      }
    }
  }
}

// ---------------- flash attention, no-P-roundtrip formulation ----------------
// Round-5 verified exact: 512 thr, grid (16,32), 2-way key split, 2-phase
// dbuf, K=32 f16 PV via permlane repack.
__global__ __launch_bounds__(512, 4) void attn_kernel(
    const u16* __restrict__ qh, const u16* __restrict__ kh,
    const u16* __restrict__ vt, u16* __restrict__ opart,
    float* __restrict__ lpart) {
  __shared__ __align__(16) u16 sK0[64 * 64], sK1[64 * 64];  // [key][dk] bf16
  __shared__ __align__(16) u16 sV0[64 * 64], sV1[64 * 64];  // [dk][key] f16
  const int t = threadIdx.x;
  const int l = t & 63, w = t >> 6;          // w 0..7
  const int ll = l & 15, lg = l >> 4;
  const int qb = blockIdx.x >> 1;            // 0..7
  const int ks = blockIdx.x & 1;             // key half
  const int q_blk = qb * 256;
  const int bh = blockIdx.y;

  // Q fragments (B-operand of 16x16x32: q=ll, dk=f*32+lg*8..+7)
  bf16x8 aq[2][2];
#pragma unroll
  for (int qt = 0; qt < 2; ++qt) {
    const u16* qbase =
        qh + ((size_t)bh * S_LEN + q_blk + w * 32 + qt * 16 + ll) * DKH;
    aq[qt][0] = ldfrag(qbase + lg * 8);
    aq[qt][1] = ldfrag(qbase + 32 + lg * 8);
  }

  f32x4 oT[2][4] = {};        // [qt][dk-tile]; C layout: q=ll, dk=nt*16+lg*4+r
  float l_part[2] = {0.f, 0.f};

  // per-thread staging geometry: thread t stages 16B chunk t of sK and of sV
  const int strow = t >> 3;                     // 0..63
  const int sgc = (t & 7) ^ (strow & 7);        // swizzled global chunk
  const u16* kstg =
      kh + ((size_t)bh * S_LEN + ks * 1024 + strow) * DKH + sgc * 8;
  const u16* vstg =
      vt + ((size_t)bh * DKH + strow) * S_LEN + ks * 1024 + sgc * 8;

  auto stg = [&](int kt, u16* dK, u16* dV) {
    gl2lds16(kstg + (size_t)kt * 64 * DKH, dK + t * 8);
    gl2lds16(vstg + kt * 64, dV + t * 8);
  };

  auto compute = [&](const u16* cK, const u16* cV) {
#pragma unroll
    for (int pr = 0; pr < 2; ++pr) {       // key window: pr*32 .. pr*32+31
      u32 pw0[4], pw1[4];  // [A0,A1,B0,B1] per qt (f16-pair words)
#pragma unroll
      for (int h = 0; h < 2; ++h) {        // 16-key sub-tile of the window
        const int krow = (pr * 2 + h) * 16 + ll;
        const bf16x8 ak0 = ldfrag(&cK[krow * 64 + (lg ^ (ll & 7)) * 8]);
        const bf16x8 ak1 = ldfrag(&cK[krow * 64 + ((4 + lg) ^ (ll & 7)) * 8]);
        f32x4 s0 = {}, s1 = {};
        s0 = mfma16(ak0, aq[0][0], s0);
        s0 = mfma16(ak1, aq[0][1], s0);
        s1 = mfma16(ak0, aq[1][0], s1);
        s1 = mfma16(ak1, aq[1][1], s1);
        {
          const float p0 = __builtin_amdgcn_exp2f(s0[0]);
          const float p1 = __builtin_amdgcn_exp2f(s0[1]);
          const float p2 = __builtin_amdgcn_exp2f(s0[2]);
          const float p3 = __builtin_amdgcn_exp2f(s0[3]);
          l_part[0] += (p0 + p1) + (p2 + p3);
          if (h == 0) { pw0[0] = pkh2(p0, p1); pw0[1] = pkh2(p2, p3); }
          else        { pw0[2] = pkh2(p0, p1); pw0[3] = pkh2(p2, p3); }
        }
        {
          const float p0 = __builtin_amdgcn_exp2f(s1[0]);
          const float p1 = __builtin_amdgcn_exp2f(s1[1]);
          const float p2 = __builtin_amdgcn_exp2f(s1[2]);
          const float p3 = __builtin_amdgcn_exp2f(s1[3]);
          l_part[1] += (p0 + p1) + (p2 + p3);
          if (h == 0) { pw1[0] = pkh2(p0, p1); pw1[1] = pkh2(p2, p3); }
          else        { pw1[2] = pkh2(p0, p1); pw1[3] = pkh2(p2, p3); }
        }
      }
      // ---- repack key=lg*4+r -> key=lg*8+j (K=32 B-operand) ----
      asm volatile("v_permlane32_swap_b32 %0, %1" : "+v"(pw0[0]), "+v"(pw0[2]));
      asm volatile("v_permlane16_swap_b32 %0, %1" : "+v"(pw0[0]), "+v"(pw0[2]));
      asm volatile("v_permlane32_swap_b32 %0, %1" : "+v"(pw0[1]), "+v"(pw0[3]));
      asm volatile("v_permlane16_swap_b32 %0, %1" : "+v"(pw0[1]), "+v"(pw0[3]));
      asm volatile("v_permlane32_swap_b32 %0, %1" : "+v"(pw1[0]), "+v"(pw1[2]));
      asm volatile("v_permlane16_swap_b32 %0, %1" : "+v"(pw1[0]), "+v"(pw1[2]));
      asm volatile("v_permlane32_swap_b32 %0, %1" : "+v"(pw1[1]), "+v"(pw1[3]));
      asm volatile("v_permlane16_swap_b32 %0, %1" : "+v"(pw1[1]), "+v"(pw1[3]));
      const f16x8 bp0 =
          __builtin_bit_cast(f16x8, (u32x4){pw0[0], pw0[1], pw0[2], pw0[3]});
      const f16x8 bp1 =
          __builtin_bit_cast(f16x8, (u32x4){pw1[0], pw1[1], pw1[2], pw1[3]});

      // ---- O^T += V^T . P  (16x16x32 f16 over this 32-key window) ----
#pragma unroll
      for (int nt = 0; nt < 4; ++nt) {
        const int row = nt * 16 + ll;             // dk row of sV
        const f16x8 av =
            ldfragh8(&cV[row * 64 + ((pr * 4 + lg) ^ (ll & 7)) * 8]);
        oT[0][nt] = mfmah32(av, bp0, oT[0][nt]);
        oT[1][nt] = mfmah32(av, bp1, oT[1][nt]);
      }
    }
  };

  // ---- 2-phase double-buffered main loop over 16 key tiles ----
  stg(0, sK0, sV0);
  __syncthreads();
  for (int kt2 = 0; kt2 < 8; ++kt2) {
    stg(2 * kt2 + 1, sK1, sV1);         // prefetch next tile (overlaps compute)
    compute(sK0, sV0);
    __syncthreads();
    if (kt2 < 7) stg(2 * kt2 + 2, sK0, sV0);
    compute(sK1, sV1);
    __syncthreads();
  }

  // ---- store unnormalized partials ----
#pragma unroll
  for (int qt = 0; qt < 2; ++qt) {
    float lv = l_part[qt];
    lv += __shfl_xor(lv, 16, 64);
    lv += __shfl_xor(lv, 32, 64);
    const int orow = q_blk + w * 32 + qt * 16 + ll;
    u16* obase = opart + (((size_t)(ks * 32 + bh)) * S_LEN + orow) * DKH;
#pragma unroll
    for (int nt = 0; nt < 4; ++nt) {
      u16x4 o;
#pragma unroll
      for (int r = 0; r < 4; ++r) o[r] = f2bf(oT[qt][nt][r]);
      *(u16x4*)&obase[nt * 16 + lg * 4] = o;
    }
    if (lg == 0) lpart[(ks * 32 + bh) * S_LEN + orow] = lv;
  }
}

// ---------------- merge partials -> ctx  (+ WO fp32->bf16 convert) ----------
// blocks 0..2047:  ctx[b][s][h][dk] = (O0 + O1) / (l0 + l1)
// blocks 2048..3071: convert WO (1M fp32) to bf16 for out_gemm
__global__ __launch_bounds__(256) void merge_ctx(
    const u16* __restrict__ op, const float* __restrict__ lp,
    u16* __restrict__ ctx, const float* __restrict__ wo,
    u16* __restrict__ woBf) {
  if (blockIdx.x >= 2048) {
    const int i = ((blockIdx.x - 2048) * 256 + threadIdx.x) * 4;
    f32x4 f = *(const f32x4*)(wo + i);
    u16x4 o;
    o[0] = f2bf(f[0]); o[1] = f2bf(f[1]); o[2] = f2bf(f[2]); o[3] = f2bf(f[3]);
    *(u16x4*)(woBf + i) = o;
    return;
  }
  const int idx = blockIdx.x * 256 + threadIdx.x;   // 0..524287
  const int dk8 = idx & 7;
  const int q = (idx >> 3) & 2047;
  const int bh = idx >> 14;                         // 0..31
  const float inv = 1.0f / (lp[bh * S_LEN + q] + lp[(32 + bh) * S_LEN + q]);
  const u16x8 a = *(const u16x8*)&op[((size_t)bh * S_LEN + q) * DKH + dk8 * 8];
  const u16x8 c = *(const u16x8*)&op[((size_t)(32 + bh) * S_LEN + q) * DKH + dk8 * 8];
  u16x8 o;
#pragma unroll
  for (int r = 0; r < 8; ++r) o[r] = f2bf((bf2f(a[r]) + bf2f(c[r])) * inv);
  const int b = bh >> 4, h = bh & 15;
  *(u16x8*)&ctx[((size_t)((b * S_LEN + q) * NH + h)) * DKH + dk8 * 8] = o;
}

// ---------------- output projection GEMM ----------------
// 128x64 (M x N), BK=64, 4 waves as 2x2 of 64x32, 2-phase double-buffer.
__global__ __launch_bounds__(256) void out_gemm(
    const u16* __restrict__ Am, const u16* __restrict__ W,
    const float* __restrict__ bo, float* __restrict__ out) {
  __shared__ __align__(16) u16 sA0[128 * 64], sA1[128 * 64];  // 16 KB each
  __shared__ __align__(16) u16 sB0[64 * 64], sB1[64 * 64];    // 8 KB each
  const int t = threadIdx.x;
  const int l = t & 63, w = t >> 6;
  const int ll = l & 15, lg = l >> 4;
  const int nb = blockIdx.x;  // 0..15
  const int mb = blockIdx.y;  // 0..31
  const int wr = (w >> 1) * 64, wc = (w & 1) * 32;

  f32x4 acc[4][2] = {};

  auto stg = [&](int kt, u16* dA, u16* dB) {
    const int k0 = kt * 64;
#pragma unroll
    for (int i = 0; i < 4; ++i) {
      const int c = i * 256 + t;               // 0..1023
      const int row = c >> 3;
      const int gc = (c & 7) ^ (row & 7);
      gl2lds16(Am + (size_t)(mb * 128 + row) * DEMB + k0 + gc * 8, dA + c * 8);
      if (i < 2)
        gl2lds16(W + (size_t)(nb * 64 + row) * DEMB + k0 + gc * 8, dB + c * 8);
    }
  };

  auto comp = [&](const u16* cA, const u16* cB) {
#pragma unroll
    for (int kk = 0; kk < 2; ++kk) {
      bf16x8 af[4], bfr[2];
#pragma unroll
      for (int i2 = 0; i2 < 4; ++i2) {
        const int row = wr + i2 * 16 + ll;
        af[i2] = ldfrag(&cA[row * 64 + ((kk * 4 + lg) ^ (row & 7)) * 8]);
      }
#pragma unroll
      for (int j2 = 0; j2 < 2; ++j2) {
        const int row = wc + j2 * 16 + ll;
        bfr[j2] = ldfrag(&cB[row * 64 + ((kk * 4 + lg) ^ (row & 7)) * 8]);
      }
#pragma unroll
      for (int i2 = 0; i2 < 4; ++i2)
#pragma unroll
        for (int j2 = 0; j2 < 2; ++j2)
          acc[i2][j2] = mfma16(af[i2], bfr[j2], acc[i2][j2]);
    }
  };

  stg(0, sA0, sB0);
  __syncthreads();
  for (int kt2 = 0; kt2 < 8; ++kt2) {
    stg(2 * kt2 + 1, sA1, sB1);
    comp(sA0, sB0);
    __syncthreads();
    if (kt2 < 7) stg(2 * kt2 + 2, sA0, sB0);
    comp(sA1, sB1);
    __syncthreads();
  }

#pragma unroll
  for (int j2 = 0; j2 < 2; ++j2) {
    const int ncol = nb * 64 + wc + j2 * 16 + ll;
    const float bb = bo[ncol];
#pragma unroll
    for (int i2 = 0; i2 < 4; ++i2) {
#pragma unroll
      for (int r = 0; r < 4; ++r) {
        const int mrow = mb * 128 + wr + i2 * 16 + lg * 4 + r;
        out[(size_t)mrow * DEMB + ncol] = acc[i2][j2][r] + bb;
      }
    }
  }
}

extern "C" void kernel_launch(void* const* d_in, const int* in_sizes, int n_in,
                              void* d_out, int out_size, void* d_ws,
                              size_t ws_size, hipStream_t stream) {
  (void)in_sizes; (void)n_in; (void)out_size; (void)ws_size;
  const float* Q  = (const float*)d_in[0];
  const float* K  = (const float*)d_in[1];
  const float* V  = (const float*)d_in[2];
  const float* WQ = (const float*)d_in[3];
  const float* bQ = (const float*)d_in[4];
  const float* WK = (const float*)d_in[5];
  const float* bK = (const float*)d_in[6];
  const float* WV = (const float*)d_in[7];
  const float* bV = (const float*)d_in[8];
  const float* WO = (const float*)d_in[9];
  const float* bO = (const float*)d_in[10];
  float* out = (float*)d_out;

  // workspace (u16 units), no aliasing anywhere:
  //   Wqkv  [3072,1024]        3M   (cvt_w out, qkv in)
  //   WoBf  [1024,1024]        1M   (merge_ctx out, out_gemm in)
  //   qh/kh/vt/ctx             16M  (4M each)
  //   opart [2][32][2048][64]  8M   (attn out, merge in)
  //   lpart [2][32][2048] f32  512K
  // total ~28.5M u16 = 57 MiB <= 64 MiB ws.
  u16* ws   = (u16*)d_ws;
  u16* Wqkv = ws;
  u16* WoBf = Wqkv + (size_t)3072 * 1024;
  u16* qh   = WoBf + (size_t)1024 * 1024;   // [BH=32][S=2048][64] (pre-scaled)
  u16* kh   = qh + (size_t)32 * 2048 * 64;  // [BH][S][64]
  u16* vt   = kh + (size_t)32 * 2048 * 64;  // [BH][64][S] (transposed, f16)
  u16* ctx  = vt + (size_t)32 * 2048 * 64;  // [B][S][H][64] == [4096,1024]
  u16* opart   = ctx + (size_t)MTOT * DEMB; // [2][32][2048][64] bf16
  float* lpart = (float*)(opart + (size_t)2 * 32 * 2048 * 64);

  cvt_w<<<3072, 256, 0, stream>>>(WQ, WK, WV, Wqkv);
  qkv_gemm<<<dim3(24, 32), 256, 0, stream>>>(Q, K, V, Wqkv, bQ, bK, bV,
                                             qh, kh, vt);
  attn_kernel<<<dim3(16, 32), 512, 0, stream>>>(qh, kh, vt, opart, lpart);
  merge_ctx<<<3072, 256, 0, stream>>>(opart, lpart, ctx, WO, WoBf);
  out_gemm<<<dim3(16, 32), 256, 0, stream>>>(ctx, WoBf, bO, out);
}

// Round 11
// 221.878 us; speedup vs baseline: 1.1161x; 1.1161x over previous
//
#include <hip/hip_runtime.h>
#include <cstdint>
#include <cstddef>

// Problem constants: B=2, S=2048, D=1024, H=16, dk=64. M = B*S = 4096.
#define S_LEN 2048
#define NH    16
#define DKH   64
#define DEMB  1024
#define MTOT  4096

typedef float f32x4 __attribute__((ext_vector_type(4)));
typedef __bf16 bf16x8 __attribute__((ext_vector_type(8)));
typedef _Float16 f16;
typedef f16 f16x2 __attribute__((ext_vector_type(2)));
typedef f16 f16x4 __attribute__((ext_vector_type(4)));
typedef f16 f16x8 __attribute__((ext_vector_type(8)));
typedef unsigned short u16;
typedef unsigned int u32;
typedef u16 u16x8 __attribute__((ext_vector_type(8)));
typedef u16 u16x4 __attribute__((ext_vector_type(4)));
typedef u32 u32x4 __attribute__((ext_vector_type(4)));

static __device__ __forceinline__ u16 f2bf(float f) {
  u32 u = __builtin_bit_cast(u32, f);
  u += 0x7fffu + ((u >> 16) & 1u);          // RNE
  return (u16)(u >> 16);
}
static __device__ __forceinline__ float bf2f(u16 b) {
  return __builtin_bit_cast(float, ((u32)b) << 16);
}
static __device__ __forceinline__ bf16x8 ldfrag(const u16* p) {
  return __builtin_bit_cast(bf16x8, *(const u16x8*)p);
}
static __device__ __forceinline__ f16x8 ldfragh8(const u16* p) {
  return __builtin_bit_cast(f16x8, *(const u16x8*)p);
}
static __device__ __forceinline__ f32x4 mfma16(bf16x8 a, bf16x8 b, f32x4 c) {
  return __builtin_amdgcn_mfma_f32_16x16x32_bf16(a, b, c, 0, 0, 0);
}
static __device__ __forceinline__ f32x4 mfmah32(f16x8 a, f16x8 b, f32x4 c) {
  return __builtin_amdgcn_mfma_f32_16x16x32_f16(a, b, c, 0, 0, 0);
}
static __device__ __forceinline__ void gl2lds16(const void* g, void* l) {
  __builtin_amdgcn_global_load_lds((__attribute__((address_space(1))) void*)g,
                                   (__attribute__((address_space(3))) void*)l,
                                   16, 0, 0);
}
// pack 2 fp32 -> u32 of 2 f16 (RTZ)
static __device__ __forceinline__ u32 pkh2(float a, float b) {
  return __builtin_bit_cast(u32, __builtin_amdgcn_cvt_pkrtz(a, b));
}
static __device__ __forceinline__ f16x4 pkh4(float a, float b, float c, float d) {
  f16x2 lo = __builtin_bit_cast(f16x2, __builtin_amdgcn_cvt_pkrtz(a, b));
  f16x2 hi = __builtin_bit_cast(f16x2, __builtin_amdgcn_cvt_pkrtz(c, d));
  return __builtin_shufflevector(lo, hi, 0, 1, 2, 3);
}

// 1/sqrt(dk) * log2(e): folded into the Q projection so attention scores are
// already in the exp2 domain.
#define SCL_Q (0.125f * 1.44269504088896340736f)

// ---------------- fp32 -> bf16 convert: the 4 weight matrices only ----------
// (activations are consumed as fp32 directly by qkv_gemm's LDS staging)
__global__ __launch_bounds__(256) void cvt_w(
    const float* __restrict__ wq, const float* __restrict__ wk,
    const float* __restrict__ wv, const float* __restrict__ wo,
    u16* __restrict__ dW) {
  const int b = blockIdx.x;                       // 0..4095
  const int seg = b >> 10;
  const float* s = (seg == 0) ? wq : (seg == 1) ? wk : (seg == 2) ? wv : wo;
  u16* d = dW + (size_t)seg * (DEMB * DEMB);
  const int i = ((b & 1023) * 256 + threadIdx.x) * 4;
  f32x4 f = *(const f32x4*)(s + i);
  u16x4 o;
  o[0] = f2bf(f[0]); o[1] = f2bf(f[1]); o[2] = f2bf(f[2]); o[3] = f2bf(f[3]);
  *(u16x4*)(d + i) = o;
}

// ---------------- fused QKV projection GEMM ----------------------------------
// Round-7 structure (128x128 tile, BK=32, 2-phase gl2lds double-buffer, XCD
// swizzle over 768 blocks) with ONE change: the A operand is staged from the
// fp32 activations DIRECTLY via gl2lds into an fp32 LDS tile; the fp32->bf16
// convert happens in the LDS->fragment read (2x ds_read_b128 + 8x f2bf, same
// RNE -> bit-identical results). No register staging anywhere (round-9's T14
// trap avoided: the HBM->LDS path stays global_load_lds).
//   LDS: 2 x 16 KB (A fp32) + 2 x 8 KB (B bf16) = 48 KB -> 3 blocks/CU (same
//   effective occupancy as round-7). Deletes cvt_all's activation pass.
//   A swizzle: 8 x 16B chunks/row, gc = (c&7)^(row&7); read with same XOR.
__global__ __launch_bounds__(256) void qkv_gemm(
    const float* __restrict__ qf, const float* __restrict__ kf,
    const float* __restrict__ vf, const u16* __restrict__ W,
    const float* __restrict__ bq, const float* __restrict__ bk,
    const float* __restrict__ bv,
    u16* __restrict__ qh, u16* __restrict__ kh, u16* __restrict__ vt) {
  __shared__ __align__(16) float sA0[128 * 32], sA1[128 * 32];  // 16 KB each
  __shared__ __align__(16) u16 sB0[128 * 32], sB1[128 * 32];    // 8 KB each
  const int t = threadIdx.x;
  const int l = t & 63, w = t >> 6;
  const int ll = l & 15, lg = l >> 4;
  // bijective XCD swizzle over 768 blocks (8 XCDs x 96)
  const int orig = blockIdx.x + 24 * blockIdx.y;
  const int xcd = orig & 7, q = orig >> 3;        // q 0..95
  const int nb = q >> 2;                          // 0..23
  const int mb = xcd * 4 + (q & 3);               // 0..31
  const int which = nb >> 3;           // 0=Q,1=K,2=V
  const float* A = (which == 0) ? qf : ((which == 1) ? kf : vf);
  const int wr = (w >> 1) * 64, wc = (w & 1) * 64;

  f32x4 acc[4][4] = {};

  auto stgA = [&](int kt, float* dA) {
    const int k0 = kt * 32;
#pragma unroll
    for (int i = 0; i < 4; ++i) {
      const int c = i * 256 + t;                 // 16B chunk 0..1023
      const int row = c >> 3;                    // 0..127
      const int gc = (c & 7) ^ (row & 7);        // global col-chunk (4 floats)
      gl2lds16(A + (size_t)(mb * 128 + row) * DEMB + k0 + gc * 4, &dA[c * 4]);
    }
  };
  auto stgB = [&](int kt, u16* dB) {
    const int k0 = kt * 32;
#pragma unroll
    for (int i = 0; i < 2; ++i) {
      const int c = i * 256 + t;                 // 16B chunk 0..511
      const int row = c >> 2;                    // 0..127
      const int gc = (c & 3) ^ ((row >> 1) & 3); // global col-chunk (8 bf16)
      gl2lds16(W + (size_t)(nb * 128 + row) * DEMB + k0 + gc * 8, dB + c * 8);
    }
  };

  auto comp = [&](const float* cA, const u16* cB) {
    bf16x8 af[4], bfr[4];
#pragma unroll
    for (int i2 = 0; i2 < 4; ++i2) {
      const int row = wr + i2 * 16 + ll;
      // floats lg*8 .. lg*8+7 of this row = global 16B chunks {2lg, 2lg+1}
      const f32x4 x0 = *(const f32x4*)&cA[row * 32 + ((2 * lg) ^ (row & 7)) * 4];
      const f32x4 x1 = *(const f32x4*)&cA[row * 32 + ((2 * lg + 1) ^ (row & 7)) * 4];
      u16x8 o;
      o[0] = f2bf(x0[0]); o[1] = f2bf(x0[1]);
      o[2] = f2bf(x0[2]); o[3] = f2bf(x0[3]);
      o[4] = f2bf(x1[0]); o[5] = f2bf(x1[1]);
      o[6] = f2bf(x1[2]); o[7] = f2bf(x1[3]);
      af[i2] = __builtin_bit_cast(bf16x8, o);
    }
#pragma unroll
    for (int j2 = 0; j2 < 4; ++j2) {
      const int row = wc + j2 * 16 + ll;
      bfr[j2] = ldfrag(&cB[row * 32 + (lg ^ ((row >> 1) & 3)) * 8]);
    }
#pragma unroll
    for (int i2 = 0; i2 < 4; ++i2)
#pragma unroll
      for (int j2 = 0; j2 < 4; ++j2)
        acc[i2][j2] = mfma16(af[i2], bfr[j2], acc[i2][j2]);
  };

  // ---- 2-phase double-buffered main loop over 32 K-steps ----
  stgA(0, sA0); stgB(0, sB0);
  __syncthreads();
  for (int kt2 = 0; kt2 < 16; ++kt2) {
    stgA(2 * kt2 + 1, sA1); stgB(2 * kt2 + 1, sB1);   // prefetch next K-step
    comp(sA0, sB0);
    __syncthreads();                    // drains prefetch + read hazards
    if (kt2 < 15) { stgA(2 * kt2 + 2, sA0); stgB(2 * kt2 + 2, sB0); }
    comp(sA1, sB1);
    __syncthreads();
  }

  const float* bias = (which == 0) ? bq : ((which == 1) ? bk : bv);
  const int b = (mb * 128) >> 11;                // tile never crosses batch

  if (which == 2) {
    // V: f16 register scatter to [bh][dk][s]; 4 consecutive s per 8B store
#pragma unroll
    for (int j2 = 0; j2 < 4; ++j2) {
      const int nl = (nb * 128 + wc + j2 * 16 + ll) & 1023;
      const int h = nl >> 6, dk = nl & 63;
      const float bb = bias[nl];
      u16* base = vt + ((size_t)((b * NH + h) * DKH + dk)) * S_LEN;
#pragma unroll
      for (int i2 = 0; i2 < 4; ++i2) {
        const int s = (mb * 128 + wr + i2 * 16 + lg * 4) & 2047;
        const f16x4 pk = pkh4(acc[i2][j2][0] + bb, acc[i2][j2][1] + bb,
                              acc[i2][j2][2] + bb, acc[i2][j2][3] + bb);
        *(u16x4*)&base[s] = __builtin_bit_cast(u16x4, pk);
      }
    }
  } else {
    u16* outp = (which == 0) ? qh : kh;
    const float scl = (which == 0) ? SCL_Q : 1.0f;
#pragma unroll
    for (int j2 = 0; j2 < 4; ++j2) {
      const int nl = (nb * 128 + wc + j2 * 16 + ll) & 1023;
      const int h = nl >> 6, dk = nl & 63;
      const float bb = bias[nl];
#pragma unroll
      for (int i2 = 0; i2 < 4; ++i2) {
#pragma unroll
        for (int r = 0; r < 4; ++r) {
          const int s = (mb * 128 + wr + i2 * 16 + lg * 4 + r) & 2047;
          const float val = (acc[i2][j2][r] + bb) * scl;
          outp[((size_t)((b * NH + h) * S_LEN + s)) * DKH + dk] = f2bf(val);
        }
      }
    }
  }
}

// ---------------- flash attention, no-P-roundtrip formulation ----------------
// Round-5 verified exact: 512 thr, grid (16,32), 2-way key split, 2-phase
// dbuf, K=32 f16 PV via permlane repack.
__global__ __launch_bounds__(512, 4) void attn_kernel(
    const u16* __restrict__ qh, const u16* __restrict__ kh,
    const u16* __restrict__ vt, u16* __restrict__ opart,
    float* __restrict__ lpart) {
  __shared__ __align__(16) u16 sK0[64 * 64], sK1[64 * 64];  // [key][dk] bf16
  __shared__ __align__(16) u16 sV0[64 * 64], sV1[64 * 64];  // [dk][key] f16
  const int t = threadIdx.x;
  const int l = t & 63, w = t >> 6;          // w 0..7
  const int ll = l & 15, lg = l >> 4;
  const int qb = blockIdx.x >> 1;            // 0..7
  const int ks = blockIdx.x & 1;             // key half
  const int q_blk = qb * 256;
  const int bh = blockIdx.y;

  // Q fragments (B-operand of 16x16x32: q=ll, dk=f*32+lg*8..+7)
  bf16x8 aq[2][2];
#pragma unroll
  for (int qt = 0; qt < 2; ++qt) {
    const u16* qbase =
        qh + ((size_t)bh * S_LEN + q_blk + w * 32 + qt * 16 + ll) * DKH;
    aq[qt][0] = ldfrag(qbase + lg * 8);
    aq[qt][1] = ldfrag(qbase + 32 + lg * 8);
  }

  f32x4 oT[2][4] = {};        // [qt][dk-tile]; C layout: q=ll, dk=nt*16+lg*4+r
  float l_part[2] = {0.f, 0.f};

  // per-thread staging geometry: thread t stages 16B chunk t of sK and of sV
  const int strow = t >> 3;                     // 0..63
  const int sgc = (t & 7) ^ (strow & 7);        // swizzled global chunk
  const u16* kstg =
      kh + ((size_t)bh * S_LEN + ks * 1024 + strow) * DKH + sgc * 8;
  const u16* vstg =
      vt + ((size_t)bh * DKH + strow) * S_LEN + ks * 1024 + sgc * 8;

  auto stg = [&](int kt, u16* dK, u16* dV) {
    gl2lds16(kstg + (size_t)kt * 64 * DKH, dK + t * 8);
    gl2lds16(vstg + kt * 64, dV + t * 8);
  };

  auto compute = [&](const u16* cK, const u16* cV) {
#pragma unroll
    for (int pr = 0; pr < 2; ++pr) {       // key window: pr*32 .. pr*32+31
      u32 pw0[4], pw1[4];  // [A0,A1,B0,B1] per qt (f16-pair words)
#pragma unroll
      for (int h = 0; h < 2; ++h) {        // 16-key sub-tile of the window
        const int krow = (pr * 2 + h) * 16 + ll;
        const bf16x8 ak0 = ldfrag(&cK[krow * 64 + (lg ^ (ll & 7)) * 8]);
        const bf16x8 ak1 = ldfrag(&cK[krow * 64 + ((4 + lg) ^ (ll & 7)) * 8]);
        f32x4 s0 = {}, s1 = {};
        s0 = mfma16(ak0, aq[0][0], s0);
        s0 = mfma16(ak1, aq[0][1], s0);
        s1 = mfma16(ak0, aq[1][0], s1);
        s1 = mfma16(ak1, aq[1][1], s1);
        {
          const float p0 = __builtin_amdgcn_exp2f(s0[0]);
          const float p1 = __builtin_amdgcn_exp2f(s0[1]);
          const float p2 = __builtin_amdgcn_exp2f(s0[2]);
          const float p3 = __builtin_amdgcn_exp2f(s0[3]);
          l_part[0] += (p0 + p1) + (p2 + p3);
          if (h == 0) { pw0[0] = pkh2(p0, p1); pw0[1] = pkh2(p2, p3); }
          else        { pw0[2] = pkh2(p0, p1); pw0[3] = pkh2(p2, p3); }
        }
        {
          const float p0 = __builtin_amdgcn_exp2f(s1[0]);
          const float p1 = __builtin_amdgcn_exp2f(s1[1]);
          const float p2 = __builtin_amdgcn_exp2f(s1[2]);
          const float p3 = __builtin_amdgcn_exp2f(s1[3]);
          l_part[1] += (p0 + p1) + (p2 + p3);
          if (h == 0) { pw1[0] = pkh2(p0, p1); pw1[1] = pkh2(p2, p3); }
          else        { pw1[2] = pkh2(p0, p1); pw1[3] = pkh2(p2, p3); }
        }
      }
      // ---- repack key=lg*4+r -> key=lg*8+j (K=32 B-operand) ----
      asm volatile("v_permlane32_swap_b32 %0, %1" : "+v"(pw0[0]), "+v"(pw0[2]));
      asm volatile("v_permlane16_swap_b32 %0, %1" : "+v"(pw0[0]), "+v"(pw0[2]));
      asm volatile("v_permlane32_swap_b32 %0, %1" : "+v"(pw0[1]), "+v"(pw0[3]));
      asm volatile("v_permlane16_swap_b32 %0, %1" : "+v"(pw0[1]), "+v"(pw0[3]));
      asm volatile("v_permlane32_swap_b32 %0, %1" : "+v"(pw1[0]), "+v"(pw1[2]));
      asm volatile("v_permlane16_swap_b32 %0, %1" : "+v"(pw1[0]), "+v"(pw1[2]));
      asm volatile("v_permlane32_swap_b32 %0, %1" : "+v"(pw1[1]), "+v"(pw1[3]));
      asm volatile("v_permlane16_swap_b32 %0, %1" : "+v"(pw1[1]), "+v"(pw1[3]));
      const f16x8 bp0 =
          __builtin_bit_cast(f16x8, (u32x4){pw0[0], pw0[1], pw0[2], pw0[3]});
      const f16x8 bp1 =
          __builtin_bit_cast(f16x8, (u32x4){pw1[0], pw1[1], pw1[2], pw1[3]});

      // ---- O^T += V^T . P  (16x16x32 f16 over this 32-key window) ----
#pragma unroll
      for (int nt = 0; nt < 4; ++nt) {
        const int row = nt * 16 + ll;             // dk row of sV
        const f16x8 av =
            ldfragh8(&cV[row * 64 + ((pr * 4 + lg) ^ (ll & 7)) * 8]);
        oT[0][nt] = mfmah32(av, bp0, oT[0][nt]);
        oT[1][nt] = mfmah32(av, bp1, oT[1][nt]);
      }
    }
  };

  // ---- 2-phase double-buffered main loop over 16 key tiles ----
  stg(0, sK0, sV0);
  __syncthreads();
  for (int kt2 = 0; kt2 < 8; ++kt2) {
    stg(2 * kt2 + 1, sK1, sV1);         // prefetch next tile (overlaps compute)
    compute(sK0, sV0);
    __syncthreads();
    if (kt2 < 7) stg(2 * kt2 + 2, sK0, sV0);
    compute(sK1, sV1);
    __syncthreads();
  }

  // ---- store unnormalized partials ----
#pragma unroll
  for (int qt = 0; qt < 2; ++qt) {
    float lv = l_part[qt];
    lv += __shfl_xor(lv, 16, 64);
    lv += __shfl_xor(lv, 32, 64);
    const int orow = q_blk + w * 32 + qt * 16 + ll;
    u16* obase = opart + (((size_t)(ks * 32 + bh)) * S_LEN + orow) * DKH;
#pragma unroll
    for (int nt = 0; nt < 4; ++nt) {
      u16x4 o;
#pragma unroll
      for (int r = 0; r < 4; ++r) o[r] = f2bf(oT[qt][nt][r]);
      *(u16x4*)&obase[nt * 16 + lg * 4] = o;
    }
    if (lg == 0) lpart[(ks * 32 + bh) * S_LEN + orow] = lv;
  }
}

// ---------------- merge partials -> ctx ----------------
// ctx[b][s][h][dk] = (O0 + O1) / (l0 + l1)
__global__ __launch_bounds__(256) void merge_ctx(
    const u16* __restrict__ op, const float* __restrict__ lp,
    u16* __restrict__ ctx) {
  const int idx = blockIdx.x * 256 + threadIdx.x;   // 0..524287
  const int dk8 = idx & 7;
  const int q = (idx >> 3) & 2047;
  const int bh = idx >> 14;                         // 0..31
  const float inv = 1.0f / (lp[bh * S_LEN + q] + lp[(32 + bh) * S_LEN + q]);
  const u16x8 a = *(const u16x8*)&op[((size_t)bh * S_LEN + q) * DKH + dk8 * 8];
  const u16x8 c = *(const u16x8*)&op[((size_t)(32 + bh) * S_LEN + q) * DKH + dk8 * 8];
  u16x8 o;
#pragma unroll
  for (int r = 0; r < 8; ++r) o[r] = f2bf((bf2f(a[r]) + bf2f(c[r])) * inv);
  const int b = bh >> 4, h = bh & 15;
  *(u16x8*)&ctx[((size_t)((b * S_LEN + q) * NH + h)) * DKH + dk8 * 8] = o;
}

// ---------------- output projection GEMM ----------------
// 128x64 (M x N), BK=64, 4 waves as 2x2 of 64x32, 2-phase double-buffer.
__global__ __launch_bounds__(256) void out_gemm(
    const u16* __restrict__ Am, const u16* __restrict__ W,
    const float* __restrict__ bo, float* __restrict__ out) {
  __shared__ __align__(16) u16 sA0[128 * 64], sA1[128 * 64];  // 16 KB each
  __shared__ __align__(16) u16 sB0[64 * 64], sB1[64 * 64];    // 8 KB each
  const int t = threadIdx.x;
  const int l = t & 63, w = t >> 6;
  const int ll = l & 15, lg = l >> 4;
  const int nb = blockIdx.x;  // 0..15
  const int mb = blockIdx.y;  // 0..31
  const int wr = (w >> 1) * 64, wc = (w & 1) * 32;

  f32x4 acc[4][2] = {};

  auto stg = [&](int kt, u16* dA, u16* dB) {
    const int k0 = kt * 64;
#pragma unroll
    for (int i = 0; i < 4; ++i) {
      const int c = i * 256 + t;               // 0..1023
      const int row = c >> 3;
      const int gc = (c & 7) ^ (row & 7);
      gl2lds16(Am + (size_t)(mb * 128 + row) * DEMB + k0 + gc * 8, dA + c * 8);
      if (i < 2)
        gl2lds16(W + (size_t)(nb * 64 + row) * DEMB + k0 + gc * 8, dB + c * 8);
    }
  };

  auto comp = [&](const u16* cA, const u16* cB) {
#pragma unroll
    for (int kk = 0; kk < 2; ++kk) {
      bf16x8 af[4], bfr[2];
#pragma unroll
      for (int i2 = 0; i2 < 4; ++i2) {
        const int row = wr + i2 * 16 + ll;
        af[i2] = ldfrag(&cA[row * 64 + ((kk * 4 + lg) ^ (row & 7)) * 8]);
      }
#pragma unroll
      for (int j2 = 0; j2 < 2; ++j2) {
        const int row = wc + j2 * 16 + ll;
        bfr[j2] = ldfrag(&cB[row * 64 + ((kk * 4 + lg) ^ (row & 7)) * 8]);
      }
#pragma unroll
      for (int i2 = 0; i2 < 4; ++i2)
#pragma unroll
        for (int j2 = 0; j2 < 2; ++j2)
          acc[i2][j2] = mfma16(af[i2], bfr[j2], acc[i2][j2]);
    }
  };

  stg(0, sA0, sB0);
  __syncthreads();
  for (int kt2 = 0; kt2 < 8; ++kt2) {
    stg(2 * kt2 + 1, sA1, sB1);
    comp(sA0, sB0);
    __syncthreads();
    if (kt2 < 7) stg(2 * kt2 + 2, sA0, sB0);
    comp(sA1, sB1);
    __syncthreads();
  }

#pragma unroll
  for (int j2 = 0; j2 < 2; ++j2) {
    const int ncol = nb * 64 + wc + j2 * 16 + ll;
    const float bb = bo[ncol];
#pragma unroll
    for (int i2 = 0; i2 < 4; ++i2) {
#pragma unroll
      for (int r = 0; r < 4; ++r) {
        const int mrow = mb * 128 + wr + i2 * 16 + lg * 4 + r;
        out[(size_t)mrow * DEMB + ncol] = acc[i2][j2][r] + bb;
      }
    }
  }
}

extern "C" void kernel_launch(void* const* d_in, const int* in_sizes, int n_in,
                              void* d_out, int out_size, void* d_ws,
                              size_t ws_size, hipStream_t stream) {
  (void)in_sizes; (void)n_in; (void)out_size; (void)ws_size;
  const float* Q  = (const float*)d_in[0];
  const float* K  = (const float*)d_in[1];
  const float* V  = (const float*)d_in[2];
  const float* WQ = (const float*)d_in[3];
  const float* bQ = (const float*)d_in[4];
  const float* WK = (const float*)d_in[5];
  const float* bK = (const float*)d_in[6];
  const float* WV = (const float*)d_in[7];
  const float* bV = (const float*)d_in[8];
  const float* WO = (const float*)d_in[9];
  const float* bO = (const float*)d_in[10];
  float* out = (float*)d_out;

  // workspace (u16 units), no aliasing anywhere:
  //   Wqkv+Wo [4096,1024]      4M   (cvt_w out; qkv + out_gemm in)
  //   qh/kh/vt/ctx             16M  (4M each)
  //   opart [2][32][2048][64]  8M   (attn out, merge in)
  //   lpart [2][32][2048] f32  512K u16-equiv
  // total ~28.5M u16 = 57 MiB <= 64 MiB ws.
  u16* ws   = (u16*)d_ws;
  u16* Wqkv = ws;                           // QKV weights bf16 (3M)
  u16* Wo   = Wqkv + (size_t)3072 * 1024;   // WO bf16 (1M, seg 3 of cvt_w)
  u16* qh   = Wo + (size_t)1024 * 1024;     // [BH=32][S=2048][64] (pre-scaled)
  u16* kh   = qh + (size_t)32 * 2048 * 64;  // [BH][S][64]
  u16* vt   = kh + (size_t)32 * 2048 * 64;  // [BH][64][S] (transposed, f16)
  u16* ctx  = vt + (size_t)32 * 2048 * 64;  // [B][S][H][64] == [4096,1024]
  u16* opart   = ctx + (size_t)MTOT * DEMB; // [2][32][2048][64] bf16
  float* lpart = (float*)(opart + (size_t)2 * 32 * 2048 * 64);

  cvt_w<<<4096, 256, 0, stream>>>(WQ, WK, WV, WO, Wqkv);
  qkv_gemm<<<dim3(24, 32), 256, 0, stream>>>(Q, K, V, Wqkv, bQ, bK, bV,
                                             qh, kh, vt);
  attn_kernel<<<dim3(16, 32), 512, 0, stream>>>(qh, kh, vt, opart, lpart);
  merge_ctx<<<2048, 256, 0, stream>>>(opart, lpart, ctx);
  out_gemm<<<dim3(16, 32), 256, 0, stream>>>(ctx, Wo, bO, out);
}